// Round 6
// baseline (588.258 us; speedup 1.0000x reference)
//
#include <hip/hip_runtime.h>
#include <hip/hip_bf16.h>

// ---------------------------------------------------------------------------
// EncoderLayer on MI355X (gfx950), round 6.
// Changes vs R5 (GEMMs only): double-buffered LDS K-loop with ONE barrier per
// BK=32 iteration (attention-style): prefetch for iter j+1 issued right after
// barrier j, overlapping the whole compute phase of j. LDS 32KB/block.
// Attention / LN unchanged. Workspace: 184 MB.
// ---------------------------------------------------------------------------

#define DM    1024
#define DFF   4096
#define NH    16
#define HD    64
#define BATCH 4
#define SEQ   2048
#define TOK   (BATCH * SEQ)   // 8192

typedef __attribute__((ext_vector_type(8))) __bf16 bf16x8;
typedef __attribute__((ext_vector_type(4))) float f32x4;
typedef __attribute__((ext_vector_type(16))) float f32x16;
typedef __attribute__((ext_vector_type(4))) unsigned short u16x4;

typedef const __attribute__((address_space(1))) unsigned int* gas1_t;
typedef __attribute__((address_space(3))) unsigned int* las3_t;

__device__ __forceinline__ void gl_lds16(const void* g, void* l) {
  // async global->LDS, 16B per lane; LDS dest = wave-uniform base + lane*16
  __builtin_amdgcn_global_load_lds((gas1_t)g, (las3_t)l, 16, 0, 0);
}

__device__ __forceinline__ unsigned short f2bu(float x) {
  return __builtin_bit_cast(unsigned short, __float2bfloat16(x));
}

// pack hi16(a),hi16(b) -> (b | a<<16): bf16 truncation of two floats, 1 instr
__device__ __forceinline__ unsigned pk_bf16_trunc(float hi, float lo) {
  return __builtin_amdgcn_perm(__builtin_bit_cast(unsigned, hi),
                               __builtin_bit_cast(unsigned, lo), 0x07060302u);
}

// ---------------------------------------------------------------------------
// cast fp32 -> bf16 (vectorized x4)
// ---------------------------------------------------------------------------
__global__ __launch_bounds__(256) void cast_bf16(
    const float* __restrict__ in, unsigned short* __restrict__ out, int n4) {
  int i = blockIdx.x * 256 + threadIdx.x;
  if (i >= n4) return;
  float4 v = ((const float4*)in)[i];
  u16x4 o = {f2bu(v.x), f2bu(v.y), f2bu(v.z), f2bu(v.w)};
  ((u16x4*)out)[i] = o;
}

// ---------------------------------------------------------------------------
// out[n][k] = bf16(in[k][n])   (LDS-tiled transpose, block (32,8))
// ---------------------------------------------------------------------------
__global__ __launch_bounds__(256) void transpose_cast(
    const float* __restrict__ in, unsigned short* __restrict__ out, int K, int N) {
  __shared__ float tile[32][33];
  int n0 = blockIdx.x * 32, k0 = blockIdx.y * 32;
  int tx = threadIdx.x, ty = threadIdx.y;
#pragma unroll
  for (int i = 0; i < 4; ++i)
    tile[ty + 8 * i][tx] = in[(size_t)(k0 + ty + 8 * i) * N + n0 + tx];
  __syncthreads();
#pragma unroll
  for (int i = 0; i < 4; ++i)
    out[(size_t)(n0 + ty + 8 * i) * K + k0 + tx] = f2bu(tile[tx][ty + 8 * i]);
}

// 4 square (1024x1024) weight transposes in one launch (z selects matrix)
__global__ __launch_bounds__(256) void transpose_cast4(
    const float* __restrict__ A0, const float* __restrict__ A1,
    const float* __restrict__ A2, const float* __restrict__ A3,
    unsigned short* __restrict__ O0, unsigned short* __restrict__ O1,
    unsigned short* __restrict__ O2, unsigned short* __restrict__ O3) {
  __shared__ float tile[32][33];
  const float* in; unsigned short* out;
  switch (blockIdx.z) {
    case 0: in = A0; out = O0; break;
    case 1: in = A1; out = O1; break;
    case 2: in = A2; out = O2; break;
    default: in = A3; out = O3; break;
  }
  int n0 = blockIdx.x * 32, k0 = blockIdx.y * 32;
  int tx = threadIdx.x, ty = threadIdx.y;
#pragma unroll
  for (int i = 0; i < 4; ++i)
    tile[ty + 8 * i][tx] = in[(size_t)(k0 + ty + 8 * i) * DM + n0 + tx];
  __syncthreads();
#pragma unroll
  for (int i = 0; i < 4; ++i)
    out[(size_t)(n0 + ty + 8 * i) * DM + k0 + tx] = f2bu(tile[tx][ty + 8 * i]);
}

// ---------------------------------------------------------------------------
// GEMM mainloop (32x32x16 MFMA, double-buffered LDS, 1 barrier/iter):
// acc[2][2] += A[m0:128,K] @ Bt[n0:128,K]^T.
// 128x128 tile, 4 waves 2x2 (wave tile 64x64), BK=32.
// Buffers: As/Bs are 2 x 8KB; barrier at iter j guarantees (a) loads for
// buf[j] (issued during iter j-1) have landed (vmcnt drain), (b) all waves
// finished reading buf[j-1] -> safe to prefetch j+1 into it, no 2nd barrier.
// LDS rows: 32 elems (64B) = 4 chunks of 16B; slot sc holds logical k-chunk
// sc ^ ((row>>1)&3).
// ---------------------------------------------------------------------------
__device__ __forceinline__ void gemm_mainloop(
    const unsigned short* __restrict__ A, const unsigned short* __restrict__ Bt,
    int K, int m0, int n0, unsigned short* As, unsigned short* Bs,
    f32x16 acc[2][2]) {
  const int tid = threadIdx.x, lane = tid & 63, w = tid >> 6;
  const int l31 = lane & 31, khalf = lane >> 5;
  const int wr = w >> 1, wc = w & 1;
  const int rk = (l31 >> 1) & 3;       // reader swizzle key

  // staging decode: flat 16B-granule id f -> (row = f>>2, slot = f&3);
  // source k-chunk = (f&3) ^ ((row>>1)&3)
  const unsigned short* ag[2];
  const unsigned short* bg[2];
  char* ldsA[2]; char* ldsB[2];
#pragma unroll
  for (int i = 0; i < 2; ++i) {
    int f = (i * 4 + w) * 64 + lane;    // 0..511
    int row = f >> 2;
    int col = ((f & 3) ^ ((row >> 1) & 3)) * 8;
    ag[i] = A + (size_t)(m0 + row) * K + col;
    bg[i] = Bt + (size_t)(n0 + row) * K + col;
    ldsA[i] = (char*)As + (size_t)((i * 4 + w) * 1024);
    ldsB[i] = (char*)Bs + (size_t)((i * 4 + w) * 1024);
  }

  // stage iter 0 into buffer 0
#pragma unroll
  for (int i = 0; i < 2; ++i) {
    gl_lds16(ag[i], ldsA[i]);
    gl_lds16(bg[i], ldsB[i]);
    ag[i] += 32;
    bg[i] += 32;
  }

  const int nit = K >> 5;
  for (int it = 0; it < nit; ++it) {
    const int bo = (it & 1) * 8192;       // current buffer byte offset
    __syncthreads();  // buf[it] ready; all waves done reading buf[it-1]
    if (it + 1 < nit) {                   // prefetch it+1, overlaps compute
      const int po = 8192 - bo;
#pragma unroll
      for (int i = 0; i < 2; ++i) {
        gl_lds16(ag[i], ldsA[i] + po);
        gl_lds16(bg[i], ldsB[i] + po);
        ag[i] += 32;
        bg[i] += 32;
      }
    }
    const char* Ab = (const char*)As + bo;
    const char* Bb = (const char*)Bs + bo;
#pragma unroll
    for (int kk = 0; kk < 2; ++kk) {
      const int sw = ((kk * 2 + khalf) ^ rk) * 16;
      bf16x8 aF[2], bF[2];
#pragma unroll
      for (int t = 0; t < 2; ++t) {
        aF[t] = *(const bf16x8*)(Ab + (wr * 64 + t * 32 + l31) * 64 + sw);
        bF[t] = *(const bf16x8*)(Bb + (wc * 64 + t * 32 + l31) * 64 + sw);
      }
#pragma unroll
      for (int mi = 0; mi < 2; ++mi)
#pragma unroll
        for (int ni = 0; ni < 2; ++ni)
          acc[mi][ni] = __builtin_amdgcn_mfma_f32_32x32x16_bf16(
              aF[mi], bF[ni], acc[mi][ni], 0, 0, 0);
    }
  }
}

// C/D layout (32x32): col = lane&31, row = (reg&3) + 8*(reg>>2) + 4*(lane>>5)

// ---------------------------------------------------------------------------
// Generic C[M,N] = epi(A @ Bt^T + bias): relu flag, fp32/bf16 row-major out.
// ---------------------------------------------------------------------------
__global__ __launch_bounds__(256) void gemm_bt(
    const unsigned short* __restrict__ A, const unsigned short* __restrict__ Bt,
    const float* __restrict__ bias, void* __restrict__ Cout,
    int N, int K, float alpha, int relu, int ofp32) {
  __shared__ unsigned short As[2 * 128 * 32];   // 16KB (2 bufs)
  __shared__ unsigned short Bs[2 * 128 * 32];   // 16KB (2 bufs)
  const int tid = threadIdx.x, lane = tid & 63, w = tid >> 6;
  const int l31 = lane & 31, khalf = lane >> 5;
  const int m0 = blockIdx.y * 128, n0 = blockIdx.x * 128;
  const int wr = w >> 1, wc = w & 1;

  f32x16 acc[2][2];
#pragma unroll
  for (int mi = 0; mi < 2; ++mi)
#pragma unroll
    for (int ni = 0; ni < 2; ++ni)
#pragma unroll
      for (int r = 0; r < 16; ++r) acc[mi][ni][r] = 0.f;

  gemm_mainloop(A, Bt, K, m0, n0, As, Bs, acc);

#pragma unroll
  for (int ni = 0; ni < 2; ++ni) {
    int col = n0 + wc * 64 + ni * 32 + l31;
    float bvv = bias[col];
#pragma unroll
    for (int mi = 0; mi < 2; ++mi) {
#pragma unroll
      for (int g = 0; g < 4; ++g) {
        int rbase = m0 + wr * 64 + mi * 32 + g * 8 + khalf * 4;
#pragma unroll
        for (int r = 0; r < 4; ++r) {
          float val = alpha * (acc[mi][ni][g * 4 + r] + bvv);
          if (relu) val = fmaxf(val, 0.f);
          size_t idx = (size_t)(rbase + r) * N + col;
          if (ofp32) ((float*)Cout)[idx] = val;
          else ((unsigned short*)Cout)[idx] = f2bu(val);
        }
      }
    }
  }
}

// ---------------------------------------------------------------------------
// Fused QKV gemm. N=3072 (region 0: Q * (0.125*log2e) -> Qb rows;
// 1: K -> Kb rows; 2: V -> Vtg transposed per head [(b*16+h)*64+d][s]).
// ---------------------------------------------------------------------------
#define QSCALE 0.18033688f  // (1/sqrt(64)) * log2(e): softmax runs in exp2 domain

__global__ __launch_bounds__(256) void gemm_qkv(
    const unsigned short* __restrict__ A, const unsigned short* __restrict__ Bt,
    const float* __restrict__ bq, const float* __restrict__ bk,
    const float* __restrict__ bv,
    unsigned short* __restrict__ Qb, unsigned short* __restrict__ Kb,
    unsigned short* __restrict__ Vtg) {
  __shared__ unsigned short As[2 * 128 * 32];
  __shared__ unsigned short Bs[2 * 128 * 32];
  const int tid = threadIdx.x, lane = tid & 63, w = tid >> 6;
  const int l31 = lane & 31, khalf = lane >> 5;
  const int m0 = blockIdx.y * 128, n0 = blockIdx.x * 128;
  const int wr = w >> 1, wc = w & 1;

  f32x16 acc[2][2];
#pragma unroll
  for (int mi = 0; mi < 2; ++mi)
#pragma unroll
    for (int ni = 0; ni < 2; ++ni)
#pragma unroll
      for (int r = 0; r < 16; ++r) acc[mi][ni][r] = 0.f;

  gemm_mainloop(A, Bt, DM, m0, n0, As, Bs, acc);

  const int region = n0 >> 10;        // 0=Q 1=K 2=V
  const int nloc0 = (n0 & 1023) + wc * 64;
  if (region < 2) {
    unsigned short* Out = region ? Kb : Qb;
    const float* bias = region ? bk : bq;
    const float alpha = region ? 1.0f : QSCALE;
#pragma unroll
    for (int ni = 0; ni < 2; ++ni) {
      int col = nloc0 + ni * 32 + l31;
      float bvv = bias[col];
#pragma unroll
      for (int mi = 0; mi < 2; ++mi) {
#pragma unroll
        for (int g = 0; g < 4; ++g) {
          int rbase = m0 + wr * 64 + mi * 32 + g * 8 + khalf * 4;
#pragma unroll
          for (int r = 0; r < 4; ++r)
            Out[(size_t)(rbase + r) * DM + col] =
                f2bu(alpha * (acc[mi][ni][g * 4 + r] + bvv));
        }
      }
    }
  } else {
#pragma unroll
    for (int ni = 0; ni < 2; ++ni) {
      int col = nloc0 + ni * 32 + l31;       // d_model index of V
      float bvv = bv[col];
      int hh = col >> 6, dl = col & 63;
#pragma unroll
      for (int mi = 0; mi < 2; ++mi) {
#pragma unroll
        for (int g = 0; g < 4; ++g) {
          int sbase = m0 + wr * 64 + mi * 32 + g * 8 + khalf * 4;  // mult of 4
          int b_ = sbase >> 11, s0 = sbase & 2047;
          u16x4 pk;
#pragma unroll
          for (int r = 0; r < 4; ++r) pk[r] = f2bu(acc[mi][ni][g * 4 + r] + bvv);
          *(u16x4*)(Vtg + ((size_t)((b_ * NH + hh) * HD + dl)) * SEQ + s0) = pk;
        }
      }
    }
  }
}

// ---------------------------------------------------------------------------
// Flash attention, S^T formulation, BQ=128, NO-max exp2 softmax. (R4, as-is)
// ---------------------------------------------------------------------------
__global__ __launch_bounds__(256) void attn_kernel(
    const unsigned short* __restrict__ Q, const unsigned short* __restrict__ K,
    const unsigned short* __restrict__ Vtg, unsigned short* __restrict__ O) {
  __shared__ unsigned short Kt[2][64 * 64];   // [kv][d] swizzled, 8KB x2
  __shared__ unsigned short Vt[2][64 * 64];   // [d][kv] swizzled, 8KB x2
  __shared__ unsigned short Pt[4][32 * 64];   // per-wave [q][kv], 4KB x4
  __shared__ __align__(16) float redL[4][32];

  const int tid = threadIdx.x, lane = tid & 63, w = tid >> 6;
  const int l15 = lane & 15, quad = lane >> 4;
  const int q0 = blockIdx.x * 128;
  const int bh = blockIdx.y, b = bh >> 4, hh = bh & 15;
  const size_t tokbase = (size_t)b * SEQ;

  bf16x8 qf[2][2];
#pragma unroll
  for (int qg = 0; qg < 2; ++qg)
#pragma unroll
    for (int kk = 0; kk < 2; ++kk)
      qf[qg][kk] = *(const bf16x8*)(Q +
          (tokbase + q0 + w * 32 + qg * 16 + l15) * DM + hh * HD + kk * 32 + quad * 8);

  float l_run[2] = {0.f, 0.f};
  f32x4 Oacc[2][4];
#pragma unroll
  for (int qg = 0; qg < 2; ++qg)
#pragma unroll
    for (int nt = 0; nt < 4; ++nt) Oacc[qg][nt] = {0.f, 0.f, 0.f, 0.f};

  char* ptw = (char*)&Pt[w][0];

  int rowS[2], csrcS[2];
#pragma unroll
  for (int i = 0; i < 2; ++i) {
    int f = (i * 4 + w) * 64 + lane;
    rowS[i] = f >> 3;
    csrcS[i] = ((f & 7) ^ (rowS[i] & 7)) * 8;
  }
  const unsigned short* kg[2];
  const unsigned short* vg[2];
  char* ldsK[2][2]; char* ldsV[2][2];
#pragma unroll
  for (int i = 0; i < 2; ++i) {
    kg[i] = K + (tokbase + rowS[i]) * DM + hh * HD + csrcS[i];
    vg[i] = Vtg + ((size_t)bh * HD + rowS[i]) * SEQ + csrcS[i];
#pragma unroll
    for (int bb = 0; bb < 2; ++bb) {
      ldsK[bb][i] = (char*)Kt[bb] + (size_t)((i * 4 + w) * 1024);
      ldsV[bb][i] = (char*)Vt[bb] + (size_t)((i * 4 + w) * 1024);
    }
  }

#pragma unroll
  for (int i = 0; i < 2; ++i) {
    gl_lds16(kg[i], ldsK[0][i]);
    gl_lds16(vg[i], ldsV[0][i]);
    kg[i] += 64 * DM;
    vg[i] += 64;
  }

  for (int j = 0; j < SEQ / 64; ++j) {
    const int buf = j & 1;
    __syncthreads();
    if (j + 1 < SEQ / 64) {
#pragma unroll
      for (int i = 0; i < 2; ++i) {
        gl_lds16(kg[i], ldsK[buf ^ 1][i]);
        gl_lds16(vg[i], ldsV[buf ^ 1][i]);
        kg[i] += 64 * DM;
        vg[i] += 64;
      }
    }

    const char* ktb = (const char*)Kt[buf];
    const char* vtb = (const char*)Vt[buf];

    f32x4 S[2][4];
#pragma unroll
    for (int qg = 0; qg < 2; ++qg)
#pragma unroll
      for (int mt = 0; mt < 4; ++mt) S[qg][mt] = {0.f, 0.f, 0.f, 0.f};
#pragma unroll
    for (int kk = 0; kk < 2; ++kk) {
#pragma unroll
      for (int mt = 0; mt < 4; ++mt) {
        bf16x8 aK = *(const bf16x8*)(ktb + (mt * 16 + l15) * 128 +
                                     (((kk * 4 + quad) ^ (l15 & 7)) * 16));
        S[0][mt] = __builtin_amdgcn_mfma_f32_16x16x32_bf16(aK, qf[0][kk], S[0][mt], 0, 0, 0);
        S[1][mt] = __builtin_amdgcn_mfma_f32_16x16x32_bf16(aK, qf[1][kk], S[1][mt], 0, 0, 0);
      }
    }

#pragma unroll
    for (int qg = 0; qg < 2; ++qg) {
      float rs = 0.f;
#pragma unroll
      for (int mt = 0; mt < 4; ++mt) {
        float p0 = __builtin_amdgcn_exp2f(S[qg][mt][0]);
        float p1 = __builtin_amdgcn_exp2f(S[qg][mt][1]);
        float p2 = __builtin_amdgcn_exp2f(S[qg][mt][2]);
        float p3 = __builtin_amdgcn_exp2f(S[qg][mt][3]);
        rs += (p0 + p1) + (p2 + p3);
        uint2 pk = {pk_bf16_trunc(p1, p0), pk_bf16_trunc(p3, p2)};
        *(uint2*)(ptw + (qg * 16 + l15) * 128 +
                  (((mt * 2 + (quad >> 1)) ^ (l15 & 7)) * 16 + (quad & 1) * 8)) = pk;
      }
      l_run[qg] += rs;
    }

#pragma unroll
    for (int kk = 0; kk < 2; ++kk) {
      bf16x8 aP[2];
#pragma unroll
      for (int qg = 0; qg < 2; ++qg)
        aP[qg] = *(const bf16x8*)(ptw + (qg * 16 + l15) * 128 +
                                  (((kk * 4 + quad) ^ (l15 & 7)) * 16));
#pragma unroll
      for (int nt = 0; nt < 4; ++nt) {
        bf16x8 bV = *(const bf16x8*)(vtb + (nt * 16 + l15) * 128 +
                                     (((kk * 4 + quad) ^ (l15 & 7)) * 16));
        Oacc[0][nt] = __builtin_amdgcn_mfma_f32_16x16x32_bf16(aP[0], bV, Oacc[0][nt], 0, 0, 0);
        Oacc[1][nt] = __builtin_amdgcn_mfma_f32_16x16x32_bf16(aP[1], bV, Oacc[1][nt], 0, 0, 0);
      }
    }
  }

#pragma unroll
  for (int qg = 0; qg < 2; ++qg) {
    l_run[qg] += __shfl_xor(l_run[qg], 16);
    l_run[qg] += __shfl_xor(l_run[qg], 32);
    if (lane < 16) redL[w][qg * 16 + l15] = l_run[qg];
  }
#pragma unroll
  for (int qg = 0; qg < 2; ++qg) {
    f32x4 lv = *(const f32x4*)&redL[w][qg * 16 + quad * 4];
    f32x4 li;
#pragma unroll
    for (int r = 0; r < 4; ++r) li[r] = 1.0f / lv[r];
#pragma unroll
    for (int nt = 0; nt < 4; ++nt)
#pragma unroll
      for (int r = 0; r < 4; ++r) {
        size_t tok = tokbase + q0 + w * 32 + qg * 16 + quad * 4 + r;
        O[tok * DM + hh * HD + nt * 16 + l15] = f2bu(Oacc[qg][nt][r] * li[r]);
      }
  }
}

// ---------------------------------------------------------------------------
// row-wise: s = base + delta; LN(s)*gamma+beta -> outf (fp32), outb (bf16 opt)
// ---------------------------------------------------------------------------
__global__ __launch_bounds__(256) void ln_res(
    const float* __restrict__ base, const float* __restrict__ delta,
    const float* __restrict__ gamma, const float* __restrict__ beta,
    float* __restrict__ outf, unsigned short* __restrict__ outb) {
  __shared__ float red[8];
  const int row = blockIdx.x, tid = threadIdx.x;
  const size_t rb = (size_t)row * DM;
  float4 xv = ((const float4*)(base + rb))[tid];
  float4 dv = ((const float4*)(delta + rb))[tid];
  float s0 = xv.x + dv.x, s1 = xv.y + dv.y, s2 = xv.z + dv.z, s3 = xv.w + dv.w;
  float t = s0 + s1 + s2 + s3;
#pragma unroll
  for (int m = 1; m < 64; m <<= 1) t += __shfl_xor(t, m);
  if ((tid & 63) == 0) red[tid >> 6] = t;
  __syncthreads();
  float mu = (red[0] + red[1] + red[2] + red[3]) * (1.0f / DM);
  float d0 = s0 - mu, d1 = s1 - mu, d2 = s2 - mu, d3 = s3 - mu;
  float v = d0 * d0 + d1 * d1 + d2 * d2 + d3 * d3;
#pragma unroll
  for (int m = 1; m < 64; m <<= 1) v += __shfl_xor(v, m);
  if ((tid & 63) == 0) red[4 + (tid >> 6)] = v;
  __syncthreads();
  float var = (red[4] + red[5] + red[6] + red[7]) * (1.0f / DM);
  float rs = rsqrtf(var + 1e-5f);
  float4 gv = ((const float4*)gamma)[tid];
  float4 bv = ((const float4*)beta)[tid];
  float o0 = d0 * rs * gv.x + bv.x;
  float o1 = d1 * rs * gv.y + bv.y;
  float o2 = d2 * rs * gv.z + bv.z;
  float o3 = d3 * rs * gv.w + bv.w;
  float4 ov = {o0, o1, o2, o3};
  ((float4*)(outf + rb))[tid] = ov;
  if (outb) {
    u16x4 ob = {f2bu(o0), f2bu(o1), f2bu(o2), f2bu(o3)};
    ((u16x4*)(outb + rb))[tid] = ob;
  }
}

// ---------------------------------------------------------------------------
extern "C" void kernel_launch(void* const* d_in, const int* in_sizes, int n_in,
                              void* d_out, int out_size, void* d_ws, size_t ws_size,
                              hipStream_t stream) {
  const float* x   = (const float*)d_in[0];
  const float* Wq  = (const float*)d_in[1];  const float* bq  = (const float*)d_in[2];
  const float* Wk  = (const float*)d_in[3];  const float* bk  = (const float*)d_in[4];
  const float* Wv  = (const float*)d_in[5];  const float* bvv = (const float*)d_in[6];
  const float* Wo  = (const float*)d_in[7];  const float* bo  = (const float*)d_in[8];
  const float* W1  = (const float*)d_in[9];  const float* b1  = (const float*)d_in[10];
  const float* W2  = (const float*)d_in[11]; const float* b2  = (const float*)d_in[12];
  const float* g1  = (const float*)d_in[13]; const float* be1 = (const float*)d_in[14];
  const float* g2  = (const float*)d_in[15]; const float* be2 = (const float*)d_in[16];

  char* ws = (char*)d_ws;
  const size_t MB = 1ull << 20;
  unsigned short* xb    = (unsigned short*)(ws + 0 * MB);    // 16MB (later hb alias)
  unsigned short* wqkvT = (unsigned short*)(ws + 16 * MB);   // 6MB  [3072][1024]
  unsigned short* woT   = (unsigned short*)(ws + 22 * MB);   // 2MB
  unsigned short* w1T   = (unsigned short*)(ws + 24 * MB);   // 8MB
  unsigned short* w2T   = (unsigned short*)(ws + 32 * MB);   // 8MB
  unsigned short* Qb    = (unsigned short*)(ws + 40 * MB);   // 16MB
  unsigned short* Kb    = (unsigned short*)(ws + 56 * MB);   // 16MB
  unsigned short* Vtg   = (unsigned short*)(ws + 72 * MB);   // 32MB [(b,h,d)][s]
  unsigned short* aO    = (unsigned short*)(ws + 104 * MB);  // 16MB
  float*          prj   = (float*)(ws + 120 * MB);           // 32MB fp32
  float*          h     = (float*)(ws + 152 * MB);           // 32MB fp32
  unsigned short* hb    = (unsigned short*)(ws + 0 * MB);    // alias xb (dead)
  unsigned short* ffm   = (unsigned short*)(ws + 40 * MB);   // 64MB alias Qb..Vtg
  float*          ffo   = (float*)(ws + 104 * MB);           // 32MB alias aO+prj
  (void)ws_size; (void)in_sizes; (void)n_in; (void)out_size;

  // prep: cast x; weight transposes (B^T bf16); Wq/Wk/Wv stacked -> wqkvT
  cast_bf16<<<TOK * DM / 4 / 256, 256, 0, stream>>>(x, xb, TOK * DM / 4);
  transpose_cast4<<<dim3(DM / 32, DM / 32, 4), dim3(32, 8), 0, stream>>>(
      Wq, Wk, Wv, Wo, wqkvT, wqkvT + 1024 * 1024, wqkvT + 2048 * 1024, woT);
  transpose_cast<<<dim3(DFF / 32, DM / 32), dim3(32, 8), 0, stream>>>(W1, w1T, DM, DFF);
  transpose_cast<<<dim3(DM / 32, DFF / 32), dim3(32, 8), 0, stream>>>(W2, w2T, DFF, DM);

  // fused QKV projection (Q scaled for exp2-domain softmax; V transposed)
  gemm_qkv<<<dim3(3 * DM / 128, TOK / 128), 256, 0, stream>>>(
      xb, wqkvT, bq, bk, bvv, Qb, Kb, Vtg);

  // attention
  attn_kernel<<<dim3(SEQ / 128, BATCH * NH), 256, 0, stream>>>(Qb, Kb, Vtg, aO);

  // output projection (fp32 out for residual precision)
  gemm_bt<<<dim3(DM / 128, TOK / 128), 256, 0, stream>>>(aO, woT, bo, prj, DM, DM, 1.0f, 0, 1);
  // LN1: h = LN(x + prj) -> fp32 h + bf16 hb
  ln_res<<<TOK, 256, 0, stream>>>(x, prj, g1, be1, h, hb);

  // FF
  gemm_bt<<<dim3(DFF / 128, TOK / 128), 256, 0, stream>>>(hb, w1T, b1, ffm, DFF, DM, 1.0f, 1, 0);
  gemm_bt<<<dim3(DM / 128, TOK / 128), 256, 0, stream>>>(ffm, w2T, b2, ffo, DM, DFF, 1.0f, 0, 1);

  // LN2 -> d_out (fp32)
  ln_res<<<TOK, 256, 0, stream>>>(h, ffo, g2, be2, (float*)d_out, nullptr);
}